// Round 1
// baseline (1593.597 us; speedup 1.0000x reference)
//
#include <hip/hip_runtime.h>
#include <hip/hip_bf16.h>
#include <math.h>

#define NHEAD 4
#define DHEAD 64
#define HD 256      // NHEAD*DHEAD
#define PDIM 32
#define LDH 288     // HD + PDIM, row stride of the persistent h buffer

// ---------------- edge index build (counting sort by dst) ----------------
__global__ void k_count(const int* __restrict__ dst, int* __restrict__ counts, int E) {
  int i = blockIdx.x * blockDim.x + threadIdx.x;
  if (i < E) atomicAdd(&counts[dst[i]], 1);
}

__global__ void k_scan(const int* __restrict__ counts, int* __restrict__ row_start, int Nn) {
  __shared__ int buf[1024];
  __shared__ int carry_s;
  int t = threadIdx.x;
  if (t == 0) carry_s = 0;
  __syncthreads();
  for (int base = 0; base < Nn; base += 1024) {
    int v = (base + t < Nn) ? counts[base + t] : 0;
    buf[t] = v;
    __syncthreads();
    for (int off = 1; off < 1024; off <<= 1) {
      int x = (t >= off) ? buf[t - off] : 0;
      __syncthreads();
      buf[t] += x;
      __syncthreads();
    }
    int incl = buf[t];
    int carry = carry_s;
    if (base + t < Nn) row_start[base + t] = carry + incl - v;
    __syncthreads();
    if (t == 1023) carry_s = carry + incl;
    __syncthreads();
  }
  if (t == 0) row_start[Nn] = carry_s;
}

__global__ void k_scatter(const int* __restrict__ src, const int* __restrict__ dst,
                          const int* __restrict__ row_start, int* __restrict__ cursor,
                          int* __restrict__ esrc, int E) {
  int i = blockIdx.x * blockDim.x + threadIdx.x;
  if (i < E) {
    int d = dst[i];
    int pos = row_start[d] + atomicAdd(&cursor[d], 1);
    esrc[pos] = src[i];
  }
}

// ---------------- layer-0 input assembly: [fvs | pos_enc] ----------------
__global__ void k_build_h0(const float* __restrict__ fvs, const float* __restrict__ pe,
                           float* __restrict__ hbuf, int Nn) {
  int i = blockIdx.x * blockDim.x + threadIdx.x;
  int total = Nn * 160;
  if (i >= total) return;
  int n = i / 160, j = i - n * 160;
  hbuf[n * LDH + j] = (j < 128) ? fvs[n * 128 + j] : pe[n * PDIM + (j - 128)];
}

// ---------------- fp32 tiled GEMM: C[N,256] = X[N,K] @ B[K,256] ----------------
// grid = (ceil(N/64), 8): by 0..3 -> W -> feat, by 4..7 -> rW -> rr
__global__ __launch_bounds__(256) void k_gemm(const float* __restrict__ X, int ldX, int K,
                                              const float* __restrict__ W,
                                              const float* __restrict__ rW,
                                              float* __restrict__ feat, float* __restrict__ rr,
                                              int Nn) {
  __shared__ float Xs[32][68];  // k-major, padded for b128 alignment + bank spread
  __shared__ float Ws[32][68];
  int t = threadIdx.x;
  int row0 = blockIdx.x * 64;
  int by = blockIdx.y;
  const float* B = (by < 4) ? W : rW;
  float* C = (by < 4) ? feat : rr;
  int col0 = (by & 3) * 64;
  int tr = t >> 4, tc = t & 15;
  int r0 = tr * 4, c0 = tc * 4;
  float acc[4][4] = {};
  for (int k0 = 0; k0 < K; k0 += 32) {
    // X tile: 64 rows x 32 k  ->  Xs[k][r]
#pragma unroll
    for (int i = 0; i < 2; ++i) {
      int fidx = t + i * 256;            // 0..511 float4 slots
      int r = fidx >> 3, k4 = (fidx & 7) * 4;
      float4 v = make_float4(0.f, 0.f, 0.f, 0.f);
      int row = row0 + r;
      if (row < Nn) v = *(const float4*)&X[(size_t)row * ldX + k0 + k4];
      Xs[k4 + 0][r] = v.x;
      Xs[k4 + 1][r] = v.y;
      Xs[k4 + 2][r] = v.z;
      Xs[k4 + 3][r] = v.w;
    }
    // W tile: 32 k x 64 cols -> Ws[k][c]
#pragma unroll
    for (int i = 0; i < 2; ++i) {
      int fidx = t + i * 256;
      int kk = fidx >> 4, c4 = (fidx & 15) * 4;
      float4 v = *(const float4*)&B[(size_t)(k0 + kk) * HD + col0 + c4];
      *(float4*)&Ws[kk][c4] = v;
    }
    __syncthreads();
#pragma unroll
    for (int kk = 0; kk < 32; ++kk) {
      float4 a = *(const float4*)&Xs[kk][r0];
      float4 b = *(const float4*)&Ws[kk][c0];
      float av[4] = {a.x, a.y, a.z, a.w};
      float bv[4] = {b.x, b.y, b.z, b.w};
#pragma unroll
      for (int i2 = 0; i2 < 4; ++i2)
#pragma unroll
        for (int j = 0; j < 4; ++j)
          acc[i2][j] = fmaf(av[i2], bv[j], acc[i2][j]);
    }
    __syncthreads();
  }
#pragma unroll
  for (int i2 = 0; i2 < 4; ++i2) {
    int row = row0 + r0 + i2;
    if (row < Nn) {
      float4 v = make_float4(acc[i2][0], acc[i2][1], acc[i2][2], acc[i2][3]);
      *(float4*)&C[(size_t)row * HD + col0 + c0] = v;
    }
  }
}

// ---------------- per-node attention logits el/er ----------------
__global__ void k_elr(const float* __restrict__ feat, const float* __restrict__ al,
                      const float* __restrict__ ar, float* __restrict__ el,
                      float* __restrict__ er) {
  int n = blockIdx.x;
  int t = threadIdx.x;             // 256 = 4 heads x 64 (one wave per head)
  int h = t >> 6, d = t & 63;
  float f = feat[(size_t)n * HD + t];
  float p = f * al[h * DHEAD + d];
  float q = f * ar[h * DHEAD + d];
#pragma unroll
  for (int off = 32; off > 0; off >>= 1) {
    p += __shfl_down(p, off);
    q += __shfl_down(q, off);
  }
  if (d == 0) {
    el[n * NHEAD + h] = p;
    er[n * NHEAD + h] = q;
  }
}

// ---------------- edge softmax + aggregate + residual + elu ----------------
__global__ __launch_bounds__(256) void k_agg(const int* __restrict__ esrc,
                                             const int* __restrict__ row_start,
                                             const float* __restrict__ el,
                                             const float* __restrict__ er,
                                             const float* __restrict__ feat,
                                             const float* __restrict__ rr,
                                             const float* __restrict__ pe,
                                             float* __restrict__ hnext,
                                             float* __restrict__ out,
                                             int last, int Nn) {
  __shared__ float sm[256];
  int n = blockIdx.x;
  int t = threadIdx.x;            // 256 = (h,d)
  int h = t >> 6;
  int beg = row_start[n], end = row_start[n + 1];
  float ern = er[n * NHEAD + h];

  // pass 1: segment max of leaky_relu(el[src]+er[n])
  float m = -INFINITY;
  for (int p = beg; p < end; ++p) {
    int s = esrc[p];
    float l = el[s * NHEAD + h] + ern;
    l = (l > 0.f) ? l : 0.2f * l;
    m = fmaxf(m, l);
  }
  // pass 2: exp-weights, denom, weighted feature sum
  float acc = 0.f, denom = 0.f;
  for (int p = beg; p < end; ++p) {
    int s = esrc[p];
    float l = el[s * NHEAD + h] + ern;
    l = (l > 0.f) ? l : 0.2f * l;
    float w = __expf(l - m);
    denom += w;
    acc += w * feat[(size_t)s * HD + t];
  }
  float v = (end > beg) ? acc / denom : 0.f;
  v += rr[(size_t)n * HD + t];
  v = (v > 0.f) ? v : (__expf(v) - 1.f);   // elu

  if (!last) {
    hnext[(size_t)n * LDH + t] = v;
    if (t < PDIM) hnext[(size_t)n * LDH + HD + t] = pe[n * PDIM + t];
  } else {
    sm[t] = v;
    __syncthreads();
    if (t < DHEAD)
      out[(size_t)n * DHEAD + t] =
          0.25f * (sm[t] + sm[64 + t] + sm[128 + t] + sm[192 + t]);
    if (t < PDIM)
      out[(size_t)Nn * DHEAD + n * PDIM + t] = pe[n * PDIM + t];
  }
}

extern "C" void kernel_launch(void* const* d_in, const int* in_sizes, int n_in,
                              void* d_out, int out_size, void* d_ws, size_t ws_size,
                              hipStream_t stream) {
  const float* fvs = (const float*)d_in[0];
  const float* pe  = (const float*)d_in[1];
  const int* src = (const int*)d_in[2];
  const int* dst = (const int*)d_in[3];
  const float* W[3]  = {(const float*)d_in[4], (const float*)d_in[8],  (const float*)d_in[12]};
  const float* al[3] = {(const float*)d_in[5], (const float*)d_in[9],  (const float*)d_in[13]};
  const float* ar[3] = {(const float*)d_in[6], (const float*)d_in[10], (const float*)d_in[14]};
  const float* rW[3] = {(const float*)d_in[7], (const float*)d_in[11], (const float*)d_in[15]};
  int Nn = in_sizes[0] / 128;
  int E  = in_sizes[2];
  int Ks[3] = {160, 288, 288};

  char* ws = (char*)d_ws;
  size_t off = 0;
  auto alloc = [&](size_t bytes) {
    void* p = ws + off;
    off += (bytes + 255) & ~(size_t)255;
    return p;
  };
  float* hbuf = (float*)alloc((size_t)Nn * LDH * 4);
  float* feat = (float*)alloc((size_t)Nn * HD * 4);
  float* rr   = (float*)alloc((size_t)Nn * HD * 4);
  float* el   = (float*)alloc((size_t)Nn * NHEAD * 4);
  float* er   = (float*)alloc((size_t)Nn * NHEAD * 4);
  int* counts    = (int*)alloc((size_t)Nn * 4);
  int* cursor    = (int*)alloc((size_t)Nn * 4);
  int* row_start = (int*)alloc((size_t)(Nn + 1) * 4);
  int* esrc      = (int*)alloc((size_t)E * 4);

  hipMemsetAsync(counts, 0, (size_t)Nn * 4, stream);
  hipMemsetAsync(cursor, 0, (size_t)Nn * 4, stream);
  k_count<<<(E + 255) / 256, 256, 0, stream>>>(dst, counts, E);
  k_scan<<<1, 1024, 0, stream>>>(counts, row_start, Nn);
  k_scatter<<<(E + 255) / 256, 256, 0, stream>>>(src, dst, row_start, cursor, esrc, E);
  k_build_h0<<<(Nn * 160 + 255) / 256, 256, 0, stream>>>(fvs, pe, hbuf, Nn);

  float* out = (float*)d_out;
  for (int L = 0; L < 3; ++L) {
    dim3 g((Nn + 63) / 64, 8);
    k_gemm<<<g, 256, 0, stream>>>(hbuf, LDH, Ks[L], W[L], rW[L], feat, rr, Nn);
    k_elr<<<Nn, 256, 0, stream>>>(feat, al[L], ar[L], el, er);
    int last = (L == 2) ? 1 : 0;
    k_agg<<<Nn, 256, 0, stream>>>(esrc, row_start, el, er, feat, rr, pe, hbuf, out, last, Nn);
  }
}

// Round 2
// 884.439 us; speedup vs baseline: 1.8018x; 1.8018x over previous
//
#include <hip/hip_runtime.h>
#include <hip/hip_bf16.h>
#include <math.h>

#define NHEAD 4
#define DHEAD 64
#define HD 256      // NHEAD*DHEAD
#define PDIM 32
#define LDH 288     // HD + PDIM, row stride of the persistent h buffer

static __device__ inline ushort f2bf(float f) {
  unsigned u = __float_as_uint(f);
  unsigned r = (u + 0x7fffu + ((u >> 16) & 1u)) >> 16;   // RTNE
  return (ushort)r;
}

// ---------------- edge index build (counting sort by dst) ----------------
__global__ void k_count(const int* __restrict__ dst, int* __restrict__ counts, int E) {
  int i = blockIdx.x * blockDim.x + threadIdx.x;
  if (i < E) atomicAdd(&counts[dst[i]], 1);
}

// 3-phase exclusive scan over counts[Nn]
__global__ void k_scan1(const int* __restrict__ counts, int* __restrict__ excl,
                        int* __restrict__ bsum, int Nn) {
  __shared__ int buf[256];
  int b = blockIdx.x, t = threadIdx.x;
  int i = b * 256 + t;
  int v = (i < Nn) ? counts[i] : 0;
  buf[t] = v;
  __syncthreads();
  for (int off = 1; off < 256; off <<= 1) {
    int x = (t >= off) ? buf[t - off] : 0;
    __syncthreads();
    buf[t] += x;
    __syncthreads();
  }
  if (i < Nn) excl[i] = buf[t] - v;
  if (t == 255) bsum[b] = buf[255];
}

__global__ void k_scan2(int* __restrict__ bsum, int nb) {
  __shared__ int buf[256];
  int t = threadIdx.x;
  int v = (t < nb) ? bsum[t] : 0;
  buf[t] = v;
  __syncthreads();
  for (int off = 1; off < 256; off <<= 1) {
    int x = (t >= off) ? buf[t - off] : 0;
    __syncthreads();
    buf[t] += x;
    __syncthreads();
  }
  if (t < nb) bsum[t] = buf[t] - v;   // exclusive
}

__global__ void k_scan3(const int* __restrict__ excl, const int* __restrict__ bsum,
                        int* __restrict__ row_start, int Nn, int E) {
  int i = blockIdx.x * 256 + threadIdx.x;
  if (i < Nn) row_start[i] = excl[i] + bsum[blockIdx.x];
  if (i == 0) row_start[Nn] = E;
}

__global__ void k_scatter(const int* __restrict__ src, const int* __restrict__ dst,
                          const int* __restrict__ row_start, int* __restrict__ cursor,
                          int* __restrict__ esrc, int E) {
  int i = blockIdx.x * blockDim.x + threadIdx.x;
  if (i < E) {
    int d = dst[i];
    int pos = row_start[d] + atomicAdd(&cursor[d], 1);
    esrc[pos] = src[i];
  }
}

// ---------------- layer-0 input assembly: [fvs | pos_enc] ----------------
__global__ void k_build_h0(const float* __restrict__ fvs, const float* __restrict__ pe,
                           float* __restrict__ hbuf, int Nn) {
  int i = blockIdx.x * blockDim.x + threadIdx.x;
  int total = Nn * 160;
  if (i >= total) return;
  int n = i / 160, j = i - n * 160;
  hbuf[n * LDH + j] = (j < 128) ? fvs[n * 128 + j] : pe[n * PDIM + (j - 128)];
}

// ---------------- fp32 tiled GEMM: C[N,256] = X[N,K] @ B[K,256] ----------------
// grid = (ceil(N/64), 8): by 0..3 -> W -> featb (bf16) + el/er epilogue
//                          by 4..7 -> rW -> rr (fp32)
__global__ __launch_bounds__(256) void k_gemm(const float* __restrict__ X, int ldX, int K,
                                              const float* __restrict__ W,
                                              const float* __restrict__ rW,
                                              const float* __restrict__ al,
                                              const float* __restrict__ ar,
                                              ushort* __restrict__ featb,
                                              float* __restrict__ rr,
                                              float* __restrict__ el,
                                              float* __restrict__ er,
                                              int Nn) {
  __shared__ float Xs[32][68];  // k-major, padded
  __shared__ float Ws[32][68];
  int t = threadIdx.x;
  int row0 = blockIdx.x * 64;
  int by = blockIdx.y;
  const float* B = (by < 4) ? W : rW;
  int col0 = (by & 3) * 64;
  int tr = t >> 4, tc = t & 15;
  int r0 = tr * 4, c0 = tc * 4;
  float acc[4][4] = {};
  for (int k0 = 0; k0 < K; k0 += 32) {
#pragma unroll
    for (int i = 0; i < 2; ++i) {
      int fidx = t + i * 256;            // 0..511 float4 slots
      int r = fidx >> 3, k4 = (fidx & 7) * 4;
      float4 v = make_float4(0.f, 0.f, 0.f, 0.f);
      int row = row0 + r;
      if (row < Nn) v = *(const float4*)&X[(size_t)row * ldX + k0 + k4];
      Xs[k4 + 0][r] = v.x;
      Xs[k4 + 1][r] = v.y;
      Xs[k4 + 2][r] = v.z;
      Xs[k4 + 3][r] = v.w;
    }
#pragma unroll
    for (int i = 0; i < 2; ++i) {
      int fidx = t + i * 256;
      int kk = fidx >> 4, c4 = (fidx & 15) * 4;
      float4 v = *(const float4*)&B[(size_t)(k0 + kk) * HD + col0 + c4];
      *(float4*)&Ws[kk][c4] = v;
    }
    __syncthreads();
#pragma unroll
    for (int kk = 0; kk < 32; ++kk) {
      float4 a = *(const float4*)&Xs[kk][r0];
      float4 b = *(const float4*)&Ws[kk][c0];
      float av[4] = {a.x, a.y, a.z, a.w};
      float bv[4] = {b.x, b.y, b.z, b.w};
#pragma unroll
      for (int i2 = 0; i2 < 4; ++i2)
#pragma unroll
        for (int j = 0; j < 4; ++j)
          acc[i2][j] = fmaf(av[i2], bv[j], acc[i2][j]);
    }
    __syncthreads();
  }

  if (by < 4) {
    int hh = by;
    // el/er epilogue: this block owns ALL 64 cols of head hh for its rows
    float alr[4], arr[4];
#pragma unroll
    for (int j = 0; j < 4; ++j) {
      alr[j] = al[hh * DHEAD + c0 + j];
      arr[j] = ar[hh * DHEAD + c0 + j];
    }
    float elv[4], erv[4];
#pragma unroll
    for (int i2 = 0; i2 < 4; ++i2) {
      float e1 = 0.f, e2 = 0.f;
#pragma unroll
      for (int j = 0; j < 4; ++j) {
        e1 = fmaf(acc[i2][j], alr[j], e1);
        e2 = fmaf(acc[i2][j], arr[j], e2);
      }
      elv[i2] = e1;
      erv[i2] = e2;
    }
#pragma unroll
    for (int m = 1; m < 16; m <<= 1) {
#pragma unroll
      for (int i2 = 0; i2 < 4; ++i2) {
        elv[i2] += __shfl_xor(elv[i2], m);
        erv[i2] += __shfl_xor(erv[i2], m);
      }
    }
#pragma unroll
    for (int i2 = 0; i2 < 4; ++i2) {
      int row = row0 + r0 + i2;
      if (row < Nn) {
        ushort4 s;
        s.x = f2bf(acc[i2][0]);
        s.y = f2bf(acc[i2][1]);
        s.z = f2bf(acc[i2][2]);
        s.w = f2bf(acc[i2][3]);
        *(ushort4*)&featb[(size_t)row * HD + col0 + c0] = s;
        if (tc == 0) {
          el[row * NHEAD + hh] = elv[i2];
          er[row * NHEAD + hh] = erv[i2];
        }
      }
    }
  } else {
#pragma unroll
    for (int i2 = 0; i2 < 4; ++i2) {
      int row = row0 + r0 + i2;
      if (row < Nn) {
        float4 v = make_float4(acc[i2][0], acc[i2][1], acc[i2][2], acc[i2][3]);
        *(float4*)&rr[(size_t)row * HD + col0 + c0] = v;
      }
    }
  }
}

// ---------------- edge softmax + aggregate + residual + elu ----------------
// 256 threads = 8 half-waves; each half-wave owns one edge at a time (16B/lane).
// No segment-max pass: softmax is shift-invariant and logits are bounded small.
__global__ __launch_bounds__(256) void k_agg(const int* __restrict__ esrc,
                                             const int* __restrict__ row_start,
                                             const float* __restrict__ el,
                                             const float* __restrict__ er,
                                             const ushort* __restrict__ featb,
                                             const float* __restrict__ rr,
                                             const float* __restrict__ pe,
                                             float* __restrict__ hnext,
                                             float* __restrict__ out,
                                             int last, int Nn) {
  __shared__ float accbuf[8][HD];
  __shared__ float dnbuf[8][NHEAD];
  __shared__ float sm[HD];
  int n = blockIdx.x;
  int t = threadIdx.x;
  int g = t >> 5;          // half-wave group 0..7
  int lane = t & 31;
  int h = lane >> 3;       // head of this lane's 8 elements
  int beg = row_start[n], end = row_start[n + 1];
  float ern = er[n * NHEAD + h];

  float acc[8] = {};
  float dn = 0.f;
  for (int p = beg + g; p < end; p += 8) {
    int s = esrc[p];
    float l = el[s * NHEAD + h] + ern;
    l = (l > 0.f) ? l : 0.2f * l;
    float w = __expf(l);
    if ((lane & 7) == 0) dn += w;
    uint4 u = *(const uint4*)(featb + (size_t)s * HD + lane * 8);
#define DEC(uu, j0)                                                        \
    acc[j0]     = fmaf(w, __uint_as_float((uu) << 16), acc[j0]);           \
    acc[j0 + 1] = fmaf(w, __uint_as_float((uu) & 0xffff0000u), acc[j0 + 1]);
    DEC(u.x, 0) DEC(u.y, 2) DEC(u.z, 4) DEC(u.w, 6)
#undef DEC
  }
  *(float4*)&accbuf[g][lane * 8]     = make_float4(acc[0], acc[1], acc[2], acc[3]);
  *(float4*)&accbuf[g][lane * 8 + 4] = make_float4(acc[4], acc[5], acc[6], acc[7]);
  if ((lane & 7) == 0) dnbuf[g][h] = dn;
  __syncthreads();

  // thread t owns output element t
  float s0 = 0.f;
#pragma unroll
  for (int g2 = 0; g2 < 8; ++g2) s0 += accbuf[g2][t];
  int th = t >> 6;
  float denom = 0.f;
#pragma unroll
  for (int g2 = 0; g2 < 8; ++g2) denom += dnbuf[g2][th];

  float v = (end > beg) ? s0 / denom : 0.f;
  v += rr[(size_t)n * HD + t];
  v = (v > 0.f) ? v : (__expf(v) - 1.f);   // elu

  if (!last) {
    hnext[(size_t)n * LDH + t] = v;
    if (t < PDIM) hnext[(size_t)n * LDH + HD + t] = pe[n * PDIM + t];
  } else {
    sm[t] = v;
    __syncthreads();
    if (t < DHEAD)
      out[(size_t)n * DHEAD + t] =
          0.25f * (sm[t] + sm[64 + t] + sm[128 + t] + sm[192 + t]);
    if (t < PDIM)
      out[(size_t)Nn * DHEAD + n * PDIM + t] = pe[n * PDIM + t];
  }
}

extern "C" void kernel_launch(void* const* d_in, const int* in_sizes, int n_in,
                              void* d_out, int out_size, void* d_ws, size_t ws_size,
                              hipStream_t stream) {
  const float* fvs = (const float*)d_in[0];
  const float* pe  = (const float*)d_in[1];
  const int* src = (const int*)d_in[2];
  const int* dst = (const int*)d_in[3];
  const float* W[3]  = {(const float*)d_in[4], (const float*)d_in[8],  (const float*)d_in[12]};
  const float* al[3] = {(const float*)d_in[5], (const float*)d_in[9],  (const float*)d_in[13]};
  const float* ar[3] = {(const float*)d_in[6], (const float*)d_in[10], (const float*)d_in[14]};
  const float* rW[3] = {(const float*)d_in[7], (const float*)d_in[11], (const float*)d_in[15]};
  int Nn = in_sizes[0] / 128;
  int E  = in_sizes[2];
  int Ks[3] = {160, 288, 288};
  int nb = (Nn + 255) / 256;

  char* ws = (char*)d_ws;
  size_t off = 0;
  auto alloc = [&](size_t bytes) {
    void* p = ws + off;
    off += (bytes + 255) & ~(size_t)255;
    return p;
  };
  float* hbuf = (float*)alloc((size_t)Nn * LDH * 4);
  ushort* featb = (ushort*)alloc((size_t)Nn * HD * 2);
  float* rr   = (float*)alloc((size_t)Nn * HD * 4);
  float* el   = (float*)alloc((size_t)Nn * NHEAD * 4);
  float* er   = (float*)alloc((size_t)Nn * NHEAD * 4);
  int* counts    = (int*)alloc((size_t)Nn * 4);
  int* cursor    = (int*)alloc((size_t)Nn * 4);
  int* row_start = (int*)alloc((size_t)(Nn + 1) * 4);
  int* excl      = (int*)alloc((size_t)Nn * 4);
  int* bsum      = (int*)alloc((size_t)256 * 4);
  int* esrc      = (int*)alloc((size_t)E * 4);

  hipMemsetAsync(counts, 0, (size_t)Nn * 4, stream);
  hipMemsetAsync(cursor, 0, (size_t)Nn * 4, stream);
  k_count<<<(E + 255) / 256, 256, 0, stream>>>(dst, counts, E);
  k_scan1<<<nb, 256, 0, stream>>>(counts, excl, bsum, Nn);
  k_scan2<<<1, 256, 0, stream>>>(bsum, nb);
  k_scan3<<<nb, 256, 0, stream>>>(excl, bsum, row_start, Nn, E);
  k_scatter<<<(E + 255) / 256, 256, 0, stream>>>(src, dst, row_start, cursor, esrc, E);
  k_build_h0<<<(Nn * 160 + 255) / 256, 256, 0, stream>>>(fvs, pe, hbuf, Nn);

  float* out = (float*)d_out;
  for (int L = 0; L < 3; ++L) {
    dim3 g((Nn + 63) / 64, 8);
    k_gemm<<<g, 256, 0, stream>>>(hbuf, LDH, Ks[L], W[L], rW[L], al[L], ar[L],
                                  featb, rr, el, er, Nn);
    int last = (L == 2) ? 1 : 0;
    k_agg<<<Nn, 256, 0, stream>>>(esrc, row_start, el, er, featb, rr, pe, hbuf, out, last, Nn);
  }
}

// Round 4
// 509.571 us; speedup vs baseline: 3.1273x; 1.7357x over previous
//
#include <hip/hip_runtime.h>
#include <hip/hip_bf16.h>
#include <math.h>

#define NHEAD 4
#define DHEAD 64
#define HD 256      // NHEAD*DHEAD
#define PDIM 32
#define LDH 288     // HD + PDIM, row stride of the persistent bf16 h buffer

typedef __attribute__((ext_vector_type(8))) short bf16x8;
typedef __attribute__((ext_vector_type(4))) float f32x4;

static __device__ inline ushort f2bf(float f) {
  unsigned u = __float_as_uint(f);
  unsigned r = (u + 0x7fffu + ((u >> 16) & 1u)) >> 16;   // RTNE
  return (ushort)r;
}

// ---------------- edge index build (counting sort by dst) ----------------
__global__ void k_count(const int* __restrict__ dst, int* __restrict__ counts, int E) {
  int i = blockIdx.x * blockDim.x + threadIdx.x;
  if (i < E) atomicAdd(&counts[dst[i]], 1);
}

__global__ void k_scan1(const int* __restrict__ counts, int* __restrict__ excl,
                        int* __restrict__ bsum, int Nn) {
  __shared__ int buf[256];
  int b = blockIdx.x, t = threadIdx.x;
  int i = b * 256 + t;
  int v = (i < Nn) ? counts[i] : 0;
  buf[t] = v;
  __syncthreads();
  for (int off = 1; off < 256; off <<= 1) {
    int x = (t >= off) ? buf[t - off] : 0;
    __syncthreads();
    buf[t] += x;
    __syncthreads();
  }
  if (i < Nn) excl[i] = buf[t] - v;
  if (t == 255) bsum[b] = buf[255];
}

__global__ void k_scan2(int* __restrict__ bsum, int nb) {
  __shared__ int buf[256];
  int t = threadIdx.x;
  int v = (t < nb) ? bsum[t] : 0;
  buf[t] = v;
  __syncthreads();
  for (int off = 1; off < 256; off <<= 1) {
    int x = (t >= off) ? buf[t - off] : 0;
    __syncthreads();
    buf[t] += x;
    __syncthreads();
  }
  if (t < nb) bsum[t] = buf[t] - v;   // exclusive
}

__global__ void k_scan3(const int* __restrict__ excl, const int* __restrict__ bsum,
                        int* __restrict__ row_start, int Nn, int E) {
  int i = blockIdx.x * 256 + threadIdx.x;
  if (i < Nn) row_start[i] = excl[i] + bsum[blockIdx.x];
  if (i == 0) row_start[Nn] = E;
}

__global__ void k_scatter(const int* __restrict__ src, const int* __restrict__ dst,
                          const int* __restrict__ row_start, int* __restrict__ cursor,
                          int* __restrict__ esrc, int E) {
  int i = blockIdx.x * blockDim.x + threadIdx.x;
  if (i < E) {
    int d = dst[i];
    int pos = row_start[d] + atomicAdd(&cursor[d], 1);
    esrc[pos] = src[i];
  }
}

// ---------------- layer-0 input assembly: bf16 [fvs | pos_enc] ----------------
__global__ void k_build_h0(const float* __restrict__ fvs, const float* __restrict__ pe,
                           ushort* __restrict__ hbuf, int Nn) {
  int i = blockIdx.x * blockDim.x + threadIdx.x;
  int total = Nn * 160;
  if (i >= total) return;
  int n = i / 160, j = i - n * 160;
  float v = (j < 128) ? fvs[n * 128 + j] : pe[n * PDIM + (j - 128)];
  hbuf[n * LDH + j] = f2bf(v);
}

// ---------------- weight pack: fp32 [K,256] -> bf16 MFMA B-fragment order --------
// Bp index: ((kb*16 + colblk)*64 + lane)*8 ; lane holds B[kb*32+(lane>>4)*8+j][colblk*16+(lane&15)]
__global__ void k_pack(const float* __restrict__ W, ushort* __restrict__ Bp, int K) {
  int i = blockIdx.x * 256 + threadIdx.x;
  int total = (K >> 5) * 16 * 64;
  if (i >= total) return;
  int lane = i & 63;
  int cb = (i >> 6) & 15;
  int kb = i >> 10;
  int col = cb * 16 + (lane & 15);
  int kbase = kb * 32 + (lane >> 4) * 8;
  ushort v[8];
#pragma unroll
  for (int j = 0; j < 8; ++j) v[j] = f2bf(W[(size_t)(kbase + j) * HD + col]);
  *(uint4*)&Bp[(size_t)i * 8] = *(uint4*)v;
}

// ---------------- MFMA GEMM: C[Nn,256] = h[Nn,K] @ B[K,256] ----------------
// grid = (ceil(Nn/64), 2). by=0: Wp -> featb(bf16) + el/er epilogue. by=1: rWp -> rr(fp32).
// Block = 4 waves; wave w owns cols [w*64, w*64+64) = head w (for by=0).
__global__ __launch_bounds__(256) void k_gemm(const ushort* __restrict__ X, int K,
                                              const ushort* __restrict__ Wp,
                                              const ushort* __restrict__ rWp,
                                              const float* __restrict__ al,
                                              const float* __restrict__ ar,
                                              ushort* __restrict__ featb,
                                              float* __restrict__ rr,
                                              float* __restrict__ el,
                                              float* __restrict__ er,
                                              int Nn) {
  __shared__ float lds[4][16 * 68];   // per-wave store-transpose buffer (pad 64->68)
  int t = threadIdx.x;
  int w = t >> 6, lane = t & 63;
  int mode = blockIdx.y;
  const ushort* Bp = mode ? rWp : Wp;
  int row0 = blockIdx.x * 64;
  int col0 = w * 64;
  int lr = lane & 15, lk = lane >> 4;

  int arow[4];
#pragma unroll
  for (int m = 0; m < 4; ++m) {
    int r = row0 + m * 16 + lr;
    arow[m] = (r < Nn) ? r : (Nn - 1);
  }

  f32x4 acc[4][4] = {};
  int nkb = K >> 5;
  for (int kb = 0; kb < nkb; ++kb) {
    int k0 = kb * 32;
    bf16x8 a[4], b[4];
#pragma unroll
    for (int m = 0; m < 4; ++m)
      a[m] = *(const bf16x8*)&X[(size_t)arow[m] * LDH + k0 + lk * 8];
#pragma unroll
    for (int n = 0; n < 4; ++n)
      b[n] = *(const bf16x8*)&Bp[(((size_t)kb * 16 + (col0 >> 4) + n) * 64 + lane) * 8];
#pragma unroll
    for (int m = 0; m < 4; ++m)
#pragma unroll
      for (int n = 0; n < 4; ++n)
        acc[m][n] = __builtin_amdgcn_mfma_f32_16x16x32_bf16(a[m], b[n], acc[m][n], 0, 0, 0);
  }

  // C/D layout: within frag (m,n): row = m*16 + (lane>>4)*4 + reg, col = n*16 + (lane&15)
  if (mode == 0) {
    // fused el/er: dot feat-row with al/ar over this wave's 64 cols (= head w)
    float alv[4], arv[4];
#pragma unroll
    for (int n = 0; n < 4; ++n) {
      alv[n] = al[col0 + n * 16 + (lane & 15)];
      arv[n] = ar[col0 + n * 16 + (lane & 15)];
    }
#pragma unroll
    for (int m = 0; m < 4; ++m)
#pragma unroll
      for (int reg = 0; reg < 4; ++reg) {
        float e1 = 0.f, e2 = 0.f;
#pragma unroll
        for (int n = 0; n < 4; ++n) {
          e1 = fmaf(acc[m][n][reg], alv[n], e1);
          e2 = fmaf(acc[m][n][reg], arv[n], e2);
        }
#pragma unroll
        for (int msk = 1; msk < 16; msk <<= 1) {
          e1 += __shfl_xor(e1, msk);
          e2 += __shfl_xor(e2, msk);
        }
        int row = row0 + m * 16 + (lane >> 4) * 4 + reg;
        if ((lane & 15) == 0 && row < Nn) {
          el[row * NHEAD + w] = e1;
          er[row * NHEAD + w] = e2;
        }
      }
  }

  // store via per-wave LDS transpose for coalesced writes
  float* L = &lds[w][0];
  int r16 = lane >> 2, cbase = (lane & 3) * 16;
#pragma unroll
  for (int m = 0; m < 4; ++m) {
#pragma unroll
    for (int n = 0; n < 4; ++n)
#pragma unroll
      for (int reg = 0; reg < 4; ++reg)
        L[((lane >> 4) * 4 + reg) * 68 + n * 16 + (lane & 15)] = acc[m][n][reg];
    __syncthreads();
    int row = row0 + m * 16 + r16;
    if (row < Nn) {
      if (mode == 0) {
        ushort tmp[16];
#pragma unroll
        for (int j = 0; j < 16; ++j) tmp[j] = f2bf(L[r16 * 68 + cbase + j]);
        *(uint4*)&featb[(size_t)row * HD + col0 + cbase] = *(uint4*)&tmp[0];
        *(uint4*)&featb[(size_t)row * HD + col0 + cbase + 8] = *(uint4*)&tmp[8];
      } else {
#pragma unroll
        for (int q = 0; q < 4; ++q)
          *(float4*)&rr[(size_t)row * HD + col0 + cbase + q * 4] =
              *(float4*)&L[r16 * 68 + cbase + q * 4];
      }
    }
    __syncthreads();
  }
}

// ---------------- edge softmax + aggregate + residual + elu ----------------
__global__ __launch_bounds__(256) void k_agg(const int* __restrict__ esrc,
                                             const int* __restrict__ row_start,
                                             const float* __restrict__ el,
                                             const float* __restrict__ er,
                                             const ushort* __restrict__ featb,
                                             const float* __restrict__ rr,
                                             const float* __restrict__ pe,
                                             ushort* __restrict__ hnext,
                                             float* __restrict__ out,
                                             int last, int Nn) {
  __shared__ float accbuf[8][HD];
  __shared__ float dnbuf[8][NHEAD];
  __shared__ float sm[HD];
  int n = blockIdx.x;
  int t = threadIdx.x;
  int g = t >> 5;          // half-wave group 0..7
  int lane = t & 31;
  int h = lane >> 3;       // head of this lane's 8 elements
  int beg = row_start[n], end = row_start[n + 1];
  float ern = er[n * NHEAD + h];

  float acc[8] = {};
  float dn = 0.f;
  for (int p = beg + g; p < end; p += 8) {
    int s = esrc[p];
    float l = el[s * NHEAD + h] + ern;
    l = (l > 0.f) ? l : 0.2f * l;
    float w = __expf(l);
    if ((lane & 7) == 0) dn += w;
    uint4 u = *(const uint4*)(featb + (size_t)s * HD + lane * 8);
#define DEC(uu, j0)                                                        \
    acc[j0]     = fmaf(w, __uint_as_float((uu) << 16), acc[j0]);           \
    acc[j0 + 1] = fmaf(w, __uint_as_float((uu) & 0xffff0000u), acc[j0 + 1]);
    DEC(u.x, 0) DEC(u.y, 2) DEC(u.z, 4) DEC(u.w, 6)
#undef DEC
  }
  *(float4*)&accbuf[g][lane * 8]     = make_float4(acc[0], acc[1], acc[2], acc[3]);
  *(float4*)&accbuf[g][lane * 8 + 4] = make_float4(acc[4], acc[5], acc[6], acc[7]);
  if ((lane & 7) == 0) dnbuf[g][h] = dn;
  __syncthreads();

  float s0 = 0.f;
#pragma unroll
  for (int g2 = 0; g2 < 8; ++g2) s0 += accbuf[g2][t];
  int th = t >> 6;
  float denom = 0.f;
#pragma unroll
  for (int g2 = 0; g2 < 8; ++g2) denom += dnbuf[g2][th];

  float v = (end > beg) ? s0 / denom : 0.f;
  v += rr[(size_t)n * HD + t];
  v = (v > 0.f) ? v : (__expf(v) - 1.f);   // elu

  if (!last) {
    hnext[(size_t)n * LDH + t] = f2bf(v);
    if (t < PDIM) hnext[(size_t)n * LDH + HD + t] = f2bf(pe[n * PDIM + t]);
  } else {
    sm[t] = v;
    __syncthreads();
    if (t < DHEAD)
      out[(size_t)n * DHEAD + t] =
          0.25f * (sm[t] + sm[64 + t] + sm[128 + t] + sm[192 + t]);
    if (t < PDIM)
      out[(size_t)Nn * DHEAD + n * PDIM + t] = pe[n * PDIM + t];
  }
}

extern "C" void kernel_launch(void* const* d_in, const int* in_sizes, int n_in,
                              void* d_out, int out_size, void* d_ws, size_t ws_size,
                              hipStream_t stream) {
  const float* fvs = (const float*)d_in[0];
  const float* pe  = (const float*)d_in[1];
  const int* src = (const int*)d_in[2];
  const int* dst = (const int*)d_in[3];
  const float* W[3]  = {(const float*)d_in[4], (const float*)d_in[8],  (const float*)d_in[12]};
  const float* al[3] = {(const float*)d_in[5], (const float*)d_in[9],  (const float*)d_in[13]};
  const float* ar[3] = {(const float*)d_in[6], (const float*)d_in[10], (const float*)d_in[14]};
  const float* rW[3] = {(const float*)d_in[7], (const float*)d_in[11], (const float*)d_in[15]};
  int Nn = in_sizes[0] / 128;
  int E  = in_sizes[2];
  int Ks[3] = {160, 288, 288};
  int nb = (Nn + 255) / 256;

  char* ws = (char*)d_ws;
  size_t off = 0;
  auto alloc = [&](size_t bytes) {
    void* p = ws + off;
    off += (bytes + 255) & ~(size_t)255;
    return p;
  };
  ushort* hbuf  = (ushort*)alloc((size_t)Nn * LDH * 2);
  ushort* featb = (ushort*)alloc((size_t)Nn * HD * 2);
  float* rr   = (float*)alloc((size_t)Nn * HD * 4);
  float* el   = (float*)alloc((size_t)Nn * NHEAD * 4);
  float* er   = (float*)alloc((size_t)Nn * NHEAD * 4);
  ushort* Wp  = (ushort*)alloc((size_t)9 * 16 * 64 * 8 * 2);
  ushort* rWp = (ushort*)alloc((size_t)9 * 16 * 64 * 8 * 2);
  int* counts    = (int*)alloc((size_t)Nn * 4);
  int* cursor    = (int*)alloc((size_t)Nn * 4);
  int* row_start = (int*)alloc((size_t)(Nn + 1) * 4);
  int* excl      = (int*)alloc((size_t)Nn * 4);
  int* bsum      = (int*)alloc((size_t)256 * 4);
  int* esrc      = (int*)alloc((size_t)E * 4);

  hipMemsetAsync(counts, 0, (size_t)Nn * 4, stream);
  hipMemsetAsync(cursor, 0, (size_t)Nn * 4, stream);
  k_count<<<(E + 255) / 256, 256, 0, stream>>>(dst, counts, E);
  k_scan1<<<nb, 256, 0, stream>>>(counts, excl, bsum, Nn);
  k_scan2<<<1, 256, 0, stream>>>(bsum, nb);
  k_scan3<<<nb, 256, 0, stream>>>(excl, bsum, row_start, Nn, E);
  k_scatter<<<(E + 255) / 256, 256, 0, stream>>>(src, dst, row_start, cursor, esrc, E);
  k_build_h0<<<(Nn * 160 + 255) / 256, 256, 0, stream>>>(fvs, pe, hbuf, Nn);

  float* out = (float*)d_out;
  for (int L = 0; L < 3; ++L) {
    int npack = (Ks[L] >> 5) * 16 * 64;
    k_pack<<<(npack + 255) / 256, 256, 0, stream>>>(W[L], Wp, Ks[L]);
    k_pack<<<(npack + 255) / 256, 256, 0, stream>>>(rW[L], rWp, Ks[L]);
    dim3 g((Nn + 63) / 64, 2);
    k_gemm<<<g, 256, 0, stream>>>(hbuf, Ks[L], Wp, rWp, al[L], ar[L],
                                  featb, rr, el, er, Nn);
    int last = (L == 2) ? 1 : 0;
    k_agg<<<Nn, 256, 0, stream>>>(esrc, row_start, el, er, featb, rr, pe, hbuf, out, last, Nn);
  }
}

// Round 6
// 367.764 us; speedup vs baseline: 4.3332x; 1.3856x over previous
//
#include <hip/hip_runtime.h>
#include <hip/hip_bf16.h>
#include <math.h>

#define NHEAD 4
#define DHEAD 64
#define HD 256      // NHEAD*DHEAD
#define PDIM 32
#define LDH 288     // HD + PDIM, row stride of the persistent bf16 h buffer

typedef __attribute__((ext_vector_type(8))) short bf16x8;
typedef __attribute__((ext_vector_type(4))) float f32x4;
typedef __attribute__((ext_vector_type(2))) float f32x2;

static __device__ inline ushort f2bf(float f) {
  unsigned u = __float_as_uint(f);
  unsigned r = (u + 0x7fffu + ((u >> 16) & 1u)) >> 16;   // RTNE
  return (ushort)r;
}
static __device__ inline float bf2f(ushort s) {
  return __uint_as_float((unsigned)s << 16);
}

// ---------------- edge index build (counting sort by dst) ----------------
__global__ void k_count(const int* __restrict__ dst, int* __restrict__ counts, int E) {
  int i = blockIdx.x * blockDim.x + threadIdx.x;
  if (i < E) atomicAdd(&counts[dst[i]], 1);
}

__global__ void k_scan1(const int* __restrict__ counts, int* __restrict__ excl,
                        int* __restrict__ bsum, int Nn) {
  __shared__ int buf[256];
  int b = blockIdx.x, t = threadIdx.x;
  int i = b * 256 + t;
  int v = (i < Nn) ? counts[i] : 0;
  buf[t] = v;
  __syncthreads();
  for (int off = 1; off < 256; off <<= 1) {
    int x = (t >= off) ? buf[t - off] : 0;
    __syncthreads();
    buf[t] += x;
    __syncthreads();
  }
  if (i < Nn) excl[i] = buf[t] - v;
  if (t == 255) bsum[b] = buf[255];
}

__global__ void k_scan2(int* __restrict__ bsum, int nb) {
  __shared__ int buf[256];
  int t = threadIdx.x;
  int v = (t < nb) ? bsum[t] : 0;
  buf[t] = v;
  __syncthreads();
  for (int off = 1; off < 256; off <<= 1) {
    int x = (t >= off) ? buf[t - off] : 0;
    __syncthreads();
    buf[t] += x;
    __syncthreads();
  }
  if (t < nb) bsum[t] = buf[t] - v;   // exclusive
}

__global__ void k_scan3(const int* __restrict__ excl, const int* __restrict__ bsum,
                        int* __restrict__ row_start, int Nn, int E) {
  int i = blockIdx.x * 256 + threadIdx.x;
  if (i < Nn) row_start[i] = excl[i] + bsum[blockIdx.x];
  if (i == 0) row_start[Nn] = E;
}

__global__ void k_scatter(const int* __restrict__ src, const int* __restrict__ dst,
                          const int* __restrict__ row_start, int* __restrict__ cursor,
                          int* __restrict__ esrc, int E) {
  int i = blockIdx.x * blockDim.x + threadIdx.x;
  if (i < E) {
    int d = dst[i];
    int pos = row_start[d] + atomicAdd(&cursor[d], 1);
    esrc[pos] = src[i];
  }
}

// ---------------- layer-0 input assembly: bf16 [fvs | pos_enc] ----------------
__global__ void k_build_h0(const float* __restrict__ fvs, const float* __restrict__ pe,
                           ushort* __restrict__ hbuf, int Nn) {
  int i = blockIdx.x * blockDim.x + threadIdx.x;
  int total = Nn * 160;
  if (i >= total) return;
  int n = i / 160, j = i - n * 160;
  float v = (j < 128) ? fvs[n * 128 + j] : pe[n * PDIM + (j - 128)];
  hbuf[n * LDH + j] = f2bf(v);
}

// ---------------- weight pack: fp32 [K,256] -> bf16 MFMA B-fragment order --------
__global__ void k_pack(const float* __restrict__ W, ushort* __restrict__ Bp, int K) {
  int i = blockIdx.x * 256 + threadIdx.x;
  int total = (K >> 5) * 16 * 64;
  if (i >= total) return;
  int lane = i & 63;
  int cb = (i >> 6) & 15;
  int kb = i >> 10;
  int col = cb * 16 + (lane & 15);
  int kbase = kb * 32 + (lane >> 4) * 8;
  ushort v[8];
#pragma unroll
  for (int j = 0; j < 8; ++j) v[j] = f2bf(W[(size_t)(kbase + j) * HD + col]);
  *(uint4*)&Bp[(size_t)i * 8] = *(uint4*)v;
}

// ---------------- MFMA GEMM: C[Nn,256] = h[Nn,K] @ B[K,256] ----------------
// grid = (ceil(Nn/64), 2). by=0: Wp -> featf8 (fp8 e4m3) + el/er epilogue.
//                           by=1: rWp -> rrb (bf16).
__global__ __launch_bounds__(256) void k_gemm(const ushort* __restrict__ X, int K,
                                              const ushort* __restrict__ Wp,
                                              const ushort* __restrict__ rWp,
                                              const float* __restrict__ al,
                                              const float* __restrict__ ar,
                                              unsigned char* __restrict__ featf8,
                                              ushort* __restrict__ rrb,
                                              float* __restrict__ el,
                                              float* __restrict__ er,
                                              int Nn) {
  __shared__ float lds[4][16 * 68];   // per-wave store-transpose buffer (pad 64->68)
  int t = threadIdx.x;
  int w = t >> 6, lane = t & 63;
  int mode = blockIdx.y;
  const ushort* Bp = mode ? rWp : Wp;
  int row0 = blockIdx.x * 64;
  int col0 = w * 64;
  int lr = lane & 15, lk = lane >> 4;

  int arow[4];
#pragma unroll
  for (int m = 0; m < 4; ++m) {
    int r = row0 + m * 16 + lr;
    arow[m] = (r < Nn) ? r : (Nn - 1);
  }

  f32x4 acc[4][4] = {};
  int nkb = K >> 5;
  for (int kb = 0; kb < nkb; ++kb) {
    int k0 = kb * 32;
    bf16x8 a[4], b[4];
#pragma unroll
    for (int m = 0; m < 4; ++m)
      a[m] = *(const bf16x8*)&X[(size_t)arow[m] * LDH + k0 + lk * 8];
#pragma unroll
    for (int n = 0; n < 4; ++n)
      b[n] = *(const bf16x8*)&Bp[(((size_t)kb * 16 + (col0 >> 4) + n) * 64 + lane) * 8];
#pragma unroll
    for (int m = 0; m < 4; ++m)
#pragma unroll
      for (int n = 0; n < 4; ++n)
        acc[m][n] = __builtin_amdgcn_mfma_f32_16x16x32_bf16(a[m], b[n], acc[m][n], 0, 0, 0);
  }

  // C/D layout: within frag (m,n): row = m*16 + (lane>>4)*4 + reg, col = n*16 + (lane&15)
  if (mode == 0) {
    float alv[4], arv[4];
#pragma unroll
    for (int n = 0; n < 4; ++n) {
      alv[n] = al[col0 + n * 16 + (lane & 15)];
      arv[n] = ar[col0 + n * 16 + (lane & 15)];
    }
#pragma unroll
    for (int m = 0; m < 4; ++m)
#pragma unroll
      for (int reg = 0; reg < 4; ++reg) {
        float e1 = 0.f, e2 = 0.f;
#pragma unroll
        for (int n = 0; n < 4; ++n) {
          e1 = fmaf(acc[m][n][reg], alv[n], e1);
          e2 = fmaf(acc[m][n][reg], arv[n], e2);
        }
#pragma unroll
        for (int msk = 1; msk < 16; msk <<= 1) {
          e1 += __shfl_xor(e1, msk);
          e2 += __shfl_xor(e2, msk);
        }
        int row = row0 + m * 16 + (lane >> 4) * 4 + reg;
        if ((lane & 15) == 0 && row < Nn) {
          el[row * NHEAD + w] = e1;
          er[row * NHEAD + w] = e2;
        }
      }
  }

  // store via per-wave LDS transpose for coalesced writes
  float* L = &lds[w][0];
  int r16 = lane >> 2, cbase = (lane & 3) * 16;
#pragma unroll
  for (int m = 0; m < 4; ++m) {
#pragma unroll
    for (int n = 0; n < 4; ++n)
#pragma unroll
      for (int reg = 0; reg < 4; ++reg)
        L[((lane >> 4) * 4 + reg) * 68 + n * 16 + (lane & 15)] = acc[m][n][reg];
    __syncthreads();
    int row = row0 + m * 16 + r16;
    if (row < Nn) {
      float c[16];
#pragma unroll
      for (int j = 0; j < 16; ++j) c[j] = L[r16 * 68 + cbase + j];
      if (mode == 0) {
        unsigned d[4];
#pragma unroll
        for (int q = 0; q < 4; ++q) {
          unsigned v = 0;
          v = __builtin_amdgcn_cvt_pk_fp8_f32(c[q * 4 + 0], c[q * 4 + 1], v, false);
          v = __builtin_amdgcn_cvt_pk_fp8_f32(c[q * 4 + 2], c[q * 4 + 3], v, true);
          d[q] = v;
        }
        *(uint4*)&featf8[(size_t)row * HD + col0 + cbase] = make_uint4(d[0], d[1], d[2], d[3]);
      } else {
        ushort tmp[16];
#pragma unroll
        for (int j = 0; j < 16; ++j) tmp[j] = f2bf(c[j]);
        *(uint4*)&rrb[(size_t)row * HD + col0 + cbase] = *(uint4*)&tmp[0];
        *(uint4*)&rrb[(size_t)row * HD + col0 + cbase + 8] = *(uint4*)&tmp[8];
      }
    }
    __syncthreads();
  }
}

// ---------------- edge softmax + aggregate + residual + elu (waveized) ----------------
// One wave per node; 4 groups x 16 lanes; each group reads one full fp8 row (16B/lane).
__global__ __launch_bounds__(256) void k_agg(const int* __restrict__ esrc,
                                             const int* __restrict__ row_start,
                                             const float* __restrict__ el,
                                             const float* __restrict__ er,
                                             const unsigned char* __restrict__ featf8,
                                             const ushort* __restrict__ rrb,
                                             const float* __restrict__ pe,
                                             ushort* __restrict__ hnext,
                                             float* __restrict__ out,
                                             int last, int Nn) {
  int w = threadIdx.x >> 6;
  int lane = threadIdx.x & 63;
  int n = blockIdx.x * 4 + w;
  if (n >= Nn) return;
  int g = lane >> 4;        // group 0..3 (edge-parallel)
  int l = lane & 15;        // lane within group: cols [l*16, l*16+16)
  int h = l >> 2;           // head of these 16 cols
  int beg = row_start[n], end = row_start[n + 1];
  float ern = er[n * NHEAD + h];

  float acc[16] = {};
  float dn = 0.f;
  for (int p = beg + g; p < end; p += 4) {
    int s = esrc[p];
    float lg = el[s * NHEAD + h] + ern;
    lg = (lg > 0.f) ? lg : 0.2f * lg;
    float wgt = __expf(lg);
    dn += wgt;
    uint4 u = *(const uint4*)(featf8 + (size_t)s * HD + l * 16);
#define DEC8(uu, j0)                                                          \
    {                                                                         \
      f32x2 f0 = __builtin_amdgcn_cvt_pk_f32_fp8((int)(uu), false);           \
      f32x2 f1 = __builtin_amdgcn_cvt_pk_f32_fp8((int)(uu), true);            \
      acc[j0 + 0] = fmaf(wgt, f0[0], acc[j0 + 0]);                            \
      acc[j0 + 1] = fmaf(wgt, f0[1], acc[j0 + 1]);                            \
      acc[j0 + 2] = fmaf(wgt, f1[0], acc[j0 + 2]);                            \
      acc[j0 + 3] = fmaf(wgt, f1[1], acc[j0 + 3]);                            \
    }
    DEC8(u.x, 0) DEC8(u.y, 4) DEC8(u.z, 8) DEC8(u.w, 12)
#undef DEC8
  }
  // reduce across the 4 groups (lanes l, l+16, l+32, l+48)
  dn += __shfl_xor(dn, 16);
  dn += __shfl_xor(dn, 32);
#pragma unroll
  for (int j = 0; j < 16; ++j) {
    acc[j] += __shfl_xor(acc[j], 16);
    acc[j] += __shfl_xor(acc[j], 32);
  }

  bool has = (end > beg);
  ushort rv[16];
  *(uint4*)&rv[0] = *(const uint4*)&rrb[(size_t)n * HD + l * 16];
  *(uint4*)&rv[8] = *(const uint4*)&rrb[(size_t)n * HD + l * 16 + 8];
  float vres[16];
  float inv = has ? 1.f / dn : 0.f;
#pragma unroll
  for (int j = 0; j < 16; ++j) {
    float v = acc[j] * inv + bf2f(rv[j]);
    vres[j] = (v > 0.f) ? v : (__expf(v) - 1.f);   // elu
  }

  if (!last) {
    if (g == 0) {
      ushort o[16];
#pragma unroll
      for (int j = 0; j < 16; ++j) o[j] = f2bf(vres[j]);
      *(uint4*)&hnext[(size_t)n * LDH + l * 16] = *(uint4*)&o[0];
      *(uint4*)&hnext[(size_t)n * LDH + l * 16 + 8] = *(uint4*)&o[8];
      if (l < 2) {
        ushort o2[16];
#pragma unroll
        for (int j = 0; j < 16; ++j) o2[j] = f2bf(pe[n * PDIM + l * 16 + j]);
        *(uint4*)&hnext[(size_t)n * LDH + HD + l * 16] = *(uint4*)&o2[0];
        *(uint4*)&hnext[(size_t)n * LDH + HD + l * 16 + 8] = *(uint4*)&o2[8];
      }
    }
  } else {
    // mean over heads: lanes l, l^4, l^8 hold same within-head cols
#pragma unroll
    for (int j = 0; j < 16; ++j) {
      vres[j] += __shfl_xor(vres[j], 4);
      vres[j] += __shfl_xor(vres[j], 8);
      vres[j] *= 0.25f;
    }
    if (g == 0 && l < 4) {
#pragma unroll
      for (int q = 0; q < 4; ++q)
        *(float4*)&out[(size_t)n * DHEAD + l * 16 + q * 4] =
            make_float4(vres[q * 4], vres[q * 4 + 1], vres[q * 4 + 2], vres[q * 4 + 3]);
    }
    if (g == 0 && l >= 4 && l < 6) {
      int c0 = (l - 4) * 16;
#pragma unroll
      for (int q = 0; q < 4; ++q) {
        const float* ps = &pe[n * PDIM + c0 + q * 4];
        *(float4*)&out[(size_t)Nn * DHEAD + (size_t)n * PDIM + c0 + q * 4] =
            make_float4(ps[0], ps[1], ps[2], ps[3]);
      }
    }
  }
}

extern "C" void kernel_launch(void* const* d_in, const int* in_sizes, int n_in,
                              void* d_out, int out_size, void* d_ws, size_t ws_size,
                              hipStream_t stream) {
  const float* fvs = (const float*)d_in[0];
  const float* pe  = (const float*)d_in[1];
  const int* src = (const int*)d_in[2];
  const int* dst = (const int*)d_in[3];
  const float* W[3]  = {(const float*)d_in[4], (const float*)d_in[8],  (const float*)d_in[12]};
  const float* al[3] = {(const float*)d_in[5], (const float*)d_in[9],  (const float*)d_in[13]};
  const float* ar[3] = {(const float*)d_in[6], (const float*)d_in[10], (const float*)d_in[14]};
  const float* rW[3] = {(const float*)d_in[7], (const float*)d_in[11], (const float*)d_in[15]};
  int Nn = in_sizes[0] / 128;
  int E  = in_sizes[2];
  int Ks[3] = {160, 288, 288};
  int nb = (Nn + 255) / 256;

  char* ws = (char*)d_ws;
  size_t off = 0;
  auto alloc = [&](size_t bytes) {
    void* p = ws + off;
    off += (bytes + 255) & ~(size_t)255;
    return p;
  };
  ushort* hbuf  = (ushort*)alloc((size_t)Nn * LDH * 2);
  unsigned char* featf8 = (unsigned char*)alloc((size_t)Nn * HD);
  ushort* rrb = (ushort*)alloc((size_t)Nn * HD * 2);
  float* el   = (float*)alloc((size_t)Nn * NHEAD * 4);
  float* er   = (float*)alloc((size_t)Nn * NHEAD * 4);
  ushort* Wp  = (ushort*)alloc((size_t)9 * 16 * 64 * 8 * 2);
  ushort* rWp = (ushort*)alloc((size_t)9 * 16 * 64 * 8 * 2);
  int* counts    = (int*)alloc((size_t)Nn * 4);
  int* cursor    = (int*)alloc((size_t)Nn * 4);
  int* row_start = (int*)alloc((size_t)(Nn + 1) * 4);
  int* excl      = (int*)alloc((size_t)Nn * 4);
  int* bsum      = (int*)alloc((size_t)256 * 4);
  int* esrc      = (int*)alloc((size_t)E * 4);

  hipMemsetAsync(counts, 0, (size_t)Nn * 4, stream);
  hipMemsetAsync(cursor, 0, (size_t)Nn * 4, stream);
  k_count<<<(E + 255) / 256, 256, 0, stream>>>(dst, counts, E);
  k_scan1<<<nb, 256, 0, stream>>>(counts, excl, bsum, Nn);
  k_scan2<<<1, 256, 0, stream>>>(bsum, nb);
  k_scan3<<<nb, 256, 0, stream>>>(excl, bsum, row_start, Nn, E);
  k_scatter<<<(E + 255) / 256, 256, 0, stream>>>(src, dst, row_start, cursor, esrc, E);
  k_build_h0<<<(Nn * 160 + 255) / 256, 256, 0, stream>>>(fvs, pe, hbuf, Nn);

  float* out = (float*)d_out;
  for (int L = 0; L < 3; ++L) {
    int npack = (Ks[L] >> 5) * 16 * 64;
    k_pack<<<(npack + 255) / 256, 256, 0, stream>>>(W[L], Wp, Ks[L]);
    k_pack<<<(npack + 255) / 256, 256, 0, stream>>>(rW[L], rWp, Ks[L]);
    dim3 g((Nn + 63) / 64, 2);
    k_gemm<<<g, 256, 0, stream>>>(hbuf, Ks[L], Wp, rWp, al[L], ar[L],
                                  featf8, rrb, el, er, Nn);
    int last = (L == 2) ? 1 : 0;
    k_agg<<<(Nn + 3) / 4, 256, 0, stream>>>(esrc, row_start, el, er, featf8, rrb, pe,
                                            hbuf, out, last, Nn);
  }
}